// Round 8
// baseline (916.550 us; speedup 1.0000x reference)
//
#include <hip/hip_runtime.h>

#define TT 215
#define BB 256
#define ROWS (TT * BB)  // 55040 = 860 * 64

// ---------------------------------------------------------------- one-shot prep: ff2 transpose + timescales
__global__ void k_prep(const float* __restrict__ ff2_w, float* __restrict__ T_ff2,
                       float* __restrict__ ts) {
    int g = blockIdx.x * 256 + threadIdx.x;
    if (g < 18) ts[g] = (float)pow(215.0, (double)g / 17.0);  // matches np float64 215**linspace
    if (g < 2 * 9216) {  // ff2 [2][72][128] -> [2][j][o]
        int l = g / 9216, e = g % 9216;
        int o = e / 128, j = e % 128;
        T_ff2[l * 9216 + j * 72 + o] = ff2_w[g];
    }
}

// ---------------------------------------------------------------- x = (src[:,:,:36] @ W_enc.T + b)*6 ; grid (215,4)
__global__ __launch_bounds__(256, 1) void k_enc1(const float* __restrict__ src,
                                                 const float* __restrict__ W,
                                                 const float* __restrict__ bias,
                                                 float* __restrict__ x) {
    int row = blockIdx.x * 256 + threadIdx.x;
    int o0 = blockIdx.y * 9;
    float s[36];
    const float4* sv = (const float4*)(src + (size_t)row * 72);
#pragma unroll
    for (int k = 0; k < 9; ++k) {
        float4 v = sv[k];
        s[4 * k] = v.x; s[4 * k + 1] = v.y; s[4 * k + 2] = v.z; s[4 * k + 3] = v.w;
    }
    float* xp = x + (size_t)row * 36 + o0;
#pragma unroll
    for (int o = 0; o < 9; ++o) {
        float a = bias[o0 + o];
        const float* w = W + (size_t)(o0 + o) * 36;
#pragma unroll
        for (int i = 0; i < 36; ++i) a = fmaf(s[i], w[i], a);
        xp[o] = a * 6.0f;
    }
}

// ---------------------------------------------------------------- h[:,:, :36] = x @ Wskip.T + b ; grid (215,4)
__global__ __launch_bounds__(256, 1) void k_enc2(const float* __restrict__ x,
                                                 const float* __restrict__ W,
                                                 const float* __restrict__ bias,
                                                 float* __restrict__ h) {
    int row = blockIdx.x * 256 + threadIdx.x;
    int o0 = blockIdx.y * 9;
    float xr[36];
    const float4* xv = (const float4*)(x + (size_t)row * 36);
#pragma unroll
    for (int k = 0; k < 9; ++k) {
        float4 v = xv[k];
        xr[4 * k] = v.x; xr[4 * k + 1] = v.y; xr[4 * k + 2] = v.z; xr[4 * k + 3] = v.w;
    }
    float* hp = h + (size_t)row * 72 + o0;
#pragma unroll
    for (int o = 0; o < 9; ++o) {
        float a = bias[o0 + o];
        const float* w = W + (size_t)(o0 + o) * 36;
#pragma unroll
        for (int i = 0; i < 36; ++i) a = fmaf(xr[i], w[i], a);
        hp[o] = a;
    }
}

// ---------------------------------------------------------------- h[:,:,36:] = pe ; elementwise
__global__ __launch_bounds__(256) void k_pe(const float* __restrict__ times,
                                            const float* __restrict__ ts,
                                            float* __restrict__ h) {
    int idx = blockIdx.x * 256 + threadIdx.x;  // < ROWS*36
    int d = idx % 36, row = idx / 36;
    float t = times[row];
    float val;
    if (d < 18) val = sinf(t / ts[d]);
    else        val = cosf(t / ts[d - 18]);
    h[(size_t)row * 72 + 36 + d] = val;
}

// ---------------------------------------------------------------- graph q|k|v ; grid (36, 12): mat = y>>2, o0 = (y&3)*9
__global__ __launch_bounds__(256, 1) void k_graph_qkv(const float* __restrict__ x,
                                                      const float* __restrict__ Wq, const float* __restrict__ bq,
                                                      const float* __restrict__ Wk, const float* __restrict__ bk,
                                                      const float* __restrict__ Wv, const float* __restrict__ bv,
                                                      float* __restrict__ qg, float* __restrict__ kg,
                                                      float* __restrict__ vg) {
    int row = blockIdx.x * 256 + threadIdx.x;  // < 9216
    int mat = blockIdx.y >> 2;
    int o0 = (blockIdx.y & 3) * 9;
    const float* W; const float* bias; float* out;
    if (mat == 0)      { W = Wq; bias = bq; out = qg; }
    else if (mat == 1) { W = Wk; bias = bk; out = kg; }
    else               { W = Wv; bias = bv; out = vg; }
    float xr[36];
    const float4* xv = (const float4*)(x + (size_t)row * 36);
#pragma unroll
    for (int k = 0; k < 9; ++k) {
        float4 v = xv[k];
        xr[4 * k] = v.x; xr[4 * k + 1] = v.y; xr[4 * k + 2] = v.z; xr[4 * k + 3] = v.w;
    }
    float* op = out + (size_t)row * 36 + o0;
#pragma unroll
    for (int o = 0; o < 9; ++o) {
        float a = bias[o0 + o];
        const float* w = W + (size_t)(o0 + o) * 36;
#pragma unroll
        for (int i = 0; i < 36; ++i) a = fmaf(xr[i], w[i], a);
        op[o] = a;
    }
}

// ---------------------------------------------------------------- graph attention per batch; h[:36,:,:36] += msg
__global__ void k_graph_attn(const float* __restrict__ qg, const float* __restrict__ kg,
                             const float* __restrict__ vg, float* __restrict__ h,
                             float* __restrict__ Abuf, float* __restrict__ sqv) {
    __shared__ float q[1296], k[1296], v[1296], A[1296];
    __shared__ float red[128];
    int b = blockIdx.x, tid = threadIdx.x;
    for (int i = tid; i < 1296; i += 128) {
        int t = i / 36, e = i % 36;
        int g = (t * BB + b) * 36 + e;
        q[i] = qg[g]; k[i] = kg[g]; v[i] = vg[g];
    }
    __syncthreads();
    for (int i = tid; i < 1296; i += 128) {
        int r = i / 36, c = i % 36;
        float a = 0.f;
#pragma unroll
        for (int e = 0; e < 36; ++e) a = fmaf(q[r * 36 + e], k[c * 36 + e], a);
        A[i] = a * (1.0f / 6.0f);
    }
    __syncthreads();
    if (tid < 36) {
        float m = -1e30f;
        for (int j = 0; j < 36; ++j) m = fmaxf(m, A[tid * 36 + j]);
        float s = 0.f;
        for (int j = 0; j < 36; ++j) { float e = expf(A[tid * 36 + j] - m); A[tid * 36 + j] = e; s += e; }
        float inv = 1.0f / s;
        for (int j = 0; j < 36; ++j) A[tid * 36 + j] *= inv;
    }
    __syncthreads();
    float lsq = 0.f;
    for (int i = tid; i < 1296; i += 128) {
        float a = A[i];
        Abuf[(size_t)b * 1296 + i] = a;
        lsq = fmaf(a, a, lsq);
        int r = i / 36, e = i % 36;
        float m = 0.f;
#pragma unroll
        for (int j = 0; j < 36; ++j) m = fmaf(A[r * 36 + j], v[j * 36 + e], m);
        h[((size_t)r * BB + b) * 72 + e] += m;
    }
    red[tid] = lsq;
    __syncthreads();
    for (int s = 64; s > 0; s >>= 1) { if (tid < s) red[tid] += red[tid + s]; __syncthreads(); }
    if (tid == 0) sqv[b] = red[0];
}

// ---------------------------------------------------------------- Gram row + per-row distance partial sum
__global__ void k_gram(const float* __restrict__ Abuf, const float* __restrict__ sqv,
                       float* __restrict__ rowsum) {
    __shared__ float Arow[1296];
    __shared__ float red[256];
    int b1 = blockIdx.x, tid = threadIdx.x;
    for (int i = tid; i < 1296; i += 256) Arow[i] = Abuf[(size_t)b1 * 1296 + i];
    __syncthreads();
    int b2 = tid;
    const float* a2 = Abuf + (size_t)b2 * 1296;
    float dot = 0.f;
    for (int e = 0; e < 1296; ++e) dot = fmaf(Arow[e], a2[e], dot);
    float d2 = fmaxf(sqv[b1] + sqv[b2] - 2.0f * dot, 0.0f);
    red[tid] = (d2 > 0.0f) ? sqrtf(d2) : 0.0f;
    __syncthreads();
    for (int s = 128; s > 0; s >>= 1) { if (tid < s) red[tid] += red[tid + s]; __syncthreads(); }
    if (tid == 0) rowsum[b1] = red[0];
}

// ---------------------------------------------------------------- qkv = h @ W_in.T + b_in ; 64-row tile, 4 col-waves
// LDS-staged output, stride 217 (25 mod 32: scalar accesses cycle all banks).
// Readout is SCALAR with lane<->float mapping: consecutive lanes hit
// consecutive banks (conflict-free) and consecutive global addresses.
__global__ __launch_bounds__(256, 1) void k_qkv(const float* __restrict__ h, const float* __restrict__ W,
                                                const float* __restrict__ bias, float* __restrict__ qkv) {
    __shared__ float buf[64 * 217];
    int tid = threadIdx.x;
    size_t base = (size_t)blockIdx.x * 64 * 72;
    for (int i = tid; i < 1152; i += 256) {  // coalesced float4 staging of h tile
        float4 v = ((const float4*)(h + base))[i];
        int row = (i * 4) / 72, col = (i * 4) % 72;
        float* d = buf + row * 217 + col;
        d[0] = v.x; d[1] = v.y; d[2] = v.z; d[3] = v.w;
    }
    __syncthreads();
    int w = __builtin_amdgcn_readfirstlane(tid >> 6);  // wave-uniform col group
    int r = tid & 63;
    float hr[72];
    const float* hp = buf + r * 217;
#pragma unroll
    for (int i = 0; i < 72; ++i) hr[i] = hp[i];
    __syncthreads();  // buf is reused for the output tile below
    int o0 = w * 54;
    for (int c = 0; c < 18; ++c) {  // chunks of 3 outputs, weights via s_load
        int j0 = o0 + c * 3;
        float a0 = bias[j0], a1 = bias[j0 + 1], a2 = bias[j0 + 2];
        const float* w0 = W + (size_t)j0 * 72;
#pragma unroll
        for (int i = 0; i < 72; ++i) {
            a0 = fmaf(hr[i], w0[i], a0);
            a1 = fmaf(hr[i], w0[72 + i], a1);
            a2 = fmaf(hr[i], w0[144 + i], a2);
        }
        float* d = buf + r * 217 + j0;
        d[0] = a0; d[1] = a1; d[2] = a2;
    }
    __syncthreads();
    float* qout = qkv + (size_t)blockIdx.x * 64 * 216;
    for (int i = tid; i < 13824; i += 256) {  // scalar: bank- and line-contiguous
        int row = i / 216, col = i % 216;
        qout[i] = buf[row * 217 + col];
    }
}

// ---------------------------------------------------------------- masked MHA, block = (b, head), 128 thr, 2 queries/lane
__global__ __launch_bounds__(128, 1) void k_attn(const float* __restrict__ qkv,
                                                 const int* __restrict__ lengths,
                                                 float* __restrict__ ctx) {
    __shared__ float Ks[TT * 20];
    __shared__ float Vs[TT * 20];
    int b = blockIdx.x & (BB - 1);
    int hh = blockIdx.x >> 8;
    int tid = threadIdx.x;
    int len = lengths[b];
    int n20 = len * 20;  // only stage valid keys
    for (int i = tid; i < n20; i += 128) {
        int s = i / 20, d = i % 20;
        float kk = 0.f, vv = 0.f;
        if (d < 18) {
            size_t base2 = ((size_t)s * BB + b) * 216 + hh * 18 + d;
            kk = qkv[base2 + 72];
            vv = qkv[base2 + 144];
        }
        Ks[i] = kk; Vs[i] = vv;
    }
    __syncthreads();
    int t0 = tid, t1 = tid + 128;
    bool two = (t1 < TT);
    const float scale = 0.23570226039551587f;  // 1/sqrt(18); folded into q
    float q0[20], q1[20];
    q0[18] = q0[19] = q1[18] = q1[19] = 0.f;
    {
        const float* qb = qkv + ((size_t)t0 * BB + b) * 216 + hh * 18;
#pragma unroll
        for (int d = 0; d < 18; ++d) q0[d] = qb[d] * scale;
    }
    if (two) {
        const float* qb = qkv + ((size_t)t1 * BB + b) * 216 + hh * 18;
#pragma unroll
        for (int d = 0; d < 18; ++d) q1[d] = qb[d] * scale;
    } else {
#pragma unroll
        for (int d = 0; d < 18; ++d) q1[d] = 0.f;
    }
    // scores bounded (LN'd activations x 0.05-scale weights): exp cannot overflow -> skip online max
    float l0 = 0.f, l1 = 0.f;
    float acc0[20], acc1[20];
#pragma unroll
    for (int d = 0; d < 20; ++d) { acc0[d] = 0.f; acc1[d] = 0.f; }
    const float4* kp = (const float4*)Ks;
    const float4* vp = (const float4*)Vs;
    for (int s = 0; s < len; ++s) {
        float sc0 = 0.f, sc1 = 0.f;
#pragma unroll
        for (int c = 0; c < 5; ++c) {
            float4 kv = kp[s * 5 + c];
            sc0 = fmaf(q0[4 * c], kv.x, sc0); sc1 = fmaf(q1[4 * c], kv.x, sc1);
            sc0 = fmaf(q0[4 * c + 1], kv.y, sc0); sc1 = fmaf(q1[4 * c + 1], kv.y, sc1);
            sc0 = fmaf(q0[4 * c + 2], kv.z, sc0); sc1 = fmaf(q1[4 * c + 2], kv.z, sc1);
            sc0 = fmaf(q0[4 * c + 3], kv.w, sc0); sc1 = fmaf(q1[4 * c + 3], kv.w, sc1);
        }
        float p0 = __expf(sc0), p1 = __expf(sc1);
        l0 += p0; l1 += p1;
#pragma unroll
        for (int c = 0; c < 5; ++c) {
            float4 vv = vp[s * 5 + c];
            acc0[4 * c]     = fmaf(p0, vv.x, acc0[4 * c]);
            acc0[4 * c + 1] = fmaf(p0, vv.y, acc0[4 * c + 1]);
            acc0[4 * c + 2] = fmaf(p0, vv.z, acc0[4 * c + 2]);
            acc0[4 * c + 3] = fmaf(p0, vv.w, acc0[4 * c + 3]);
            acc1[4 * c]     = fmaf(p1, vv.x, acc1[4 * c]);
            acc1[4 * c + 1] = fmaf(p1, vv.y, acc1[4 * c + 1]);
            acc1[4 * c + 2] = fmaf(p1, vv.z, acc1[4 * c + 2]);
            acc1[4 * c + 3] = fmaf(p1, vv.w, acc1[4 * c + 3]);
        }
    }
    {
        float inv = 1.0f / l0;
        float* cb = ctx + ((size_t)t0 * BB + b) * 72 + hh * 18;
#pragma unroll
        for (int d = 0; d < 18; ++d) cb[d] = acc0[d] * inv;
    }
    if (two) {
        float inv = 1.0f / l1;
        float* cb = ctx + ((size_t)t1 * BB + b) * 72 + hh * 18;
#pragma unroll
        for (int d = 0; d < 18; ++d) cb[d] = acc1[d] * inv;
    }
}

// ---------------------------------------------------------------- h = LN(h + ctx@Wout.T+b) ; 64 rows x 4 out-waves
__global__ __launch_bounds__(256, 1) void k_outln(const float* __restrict__ ctx,
                                                  const float* __restrict__ W,
                                                  const float* __restrict__ bias,
                                                  const float* __restrict__ g,
                                                  const float* __restrict__ beta,
                                                  float* __restrict__ h) {
    __shared__ float ps[4][64], pq[4][64];
    int tid = threadIdx.x;
    int w = __builtin_amdgcn_readfirstlane(tid >> 6);  // wave-uniform -> s_load weights
    int r = tid & 63;
    size_t rowid = (size_t)blockIdx.x * 64 + r;
    int o0 = w * 18;
    float cr[72];
    const float4* cv = (const float4*)(ctx + rowid * 72);
#pragma unroll
    for (int k = 0; k < 18; ++k) {
        float4 v = cv[k];
        cr[4 * k] = v.x; cr[4 * k + 1] = v.y; cr[4 * k + 2] = v.z; cr[4 * k + 3] = v.w;
    }
    float acc[18];
#pragma unroll
    for (int oo = 0; oo < 18; oo += 3) {
        int j0 = o0 + oo;
        float a0 = bias[j0], a1 = bias[j0 + 1], a2 = bias[j0 + 2];
        const float* w0 = W + (size_t)j0 * 72;
#pragma unroll
        for (int i = 0; i < 72; ++i) {
            a0 = fmaf(cr[i], w0[i], a0);
            a1 = fmaf(cr[i], w0[72 + i], a1);
            a2 = fmaf(cr[i], w0[144 + i], a2);
        }
        acc[oo] = a0; acc[oo + 1] = a1; acc[oo + 2] = a2;
    }
    const float* hres = h + rowid * 72 + o0;
    float s = 0.f, q = 0.f;
#pragma unroll
    for (int o = 0; o < 18; ++o) {
        acc[o] += hres[o];
        s += acc[o];
        q = fmaf(acc[o], acc[o], q);
    }
    ps[w][r] = s; pq[w][r] = q;
    __syncthreads();
    float st = ps[0][r] + ps[1][r] + ps[2][r] + ps[3][r];
    float qt = pq[0][r] + pq[1][r] + pq[2][r] + pq[3][r];
    float mu = st / 72.0f;
    float var = fmaxf(qt / 72.0f - mu * mu, 0.0f);
    float rstd = 1.0f / sqrtf(var + 1e-5f);
    float* hw = h + rowid * 72 + o0;
#pragma unroll
    for (int o = 0; o < 18; ++o) hw[o] = (acc[o] - mu) * rstd * g[o0 + o] + beta[o0 + o];
}

// ---------------------------------------------------------------- h = LN(h + relu(h@ff1.T)@ff2.T+b) ; 64 rows x 4 waves
__global__ __launch_bounds__(256, 1) void k_ffln(const float* __restrict__ ff1,
                                                 const float* __restrict__ b1,
                                                 const float* __restrict__ Tff2,
                                                 const float* __restrict__ b2,
                                                 const float* __restrict__ g,
                                                 const float* __restrict__ beta,
                                                 float* __restrict__ h) {
    __shared__ float hid[64][129];  // bank = (r + j) % 32: conflict-free
    __shared__ float ps[4][64], pq[4][64];
    int tid = threadIdx.x;
    int w = __builtin_amdgcn_readfirstlane(tid >> 6);  // wave-uniform -> s_load weights
    int r = tid & 63;
    size_t rowid = (size_t)blockIdx.x * 64 + r;
    float hr[72];
    const float4* hv = (const float4*)(h + rowid * 72);
#pragma unroll
    for (int k = 0; k < 18; ++k) {
        float4 v = hv[k];
        hr[4 * k] = v.x; hr[4 * k + 1] = v.y; hr[4 * k + 2] = v.z; hr[4 * k + 3] = v.w;
    }
    int j0 = w * 32;
    for (int jj = 0; jj < 32; jj += 2) {
        int j = j0 + jj;
        float a0 = b1[j], a1 = b1[j + 1];
        const float* wp = ff1 + (size_t)j * 72;
#pragma unroll
        for (int i = 0; i < 72; ++i) {
            a0 = fmaf(hr[i], wp[i], a0);
            a1 = fmaf(hr[i], wp[72 + i], a1);
        }
        hid[r][j] = fmaxf(a0, 0.f);
        hid[r][j + 1] = fmaxf(a1, 0.f);
    }
    __syncthreads();
    int o0 = w * 18;
    float acc[18];
#pragma unroll
    for (int o = 0; o < 18; ++o) acc[o] = b2[o0 + o];
    for (int j = 0; j < 128; ++j) {
        float hj = hid[r][j];
        const float* wt = Tff2 + (size_t)j * 72 + o0;
#pragma unroll
        for (int o = 0; o < 18; ++o) acc[o] = fmaf(hj, wt[o], acc[o]);
    }
    const float* hres = h + rowid * 72 + o0;
    float s = 0.f, q = 0.f;
#pragma unroll
    for (int o = 0; o < 18; ++o) {
        acc[o] += hres[o];
        s += acc[o];
        q = fmaf(acc[o], acc[o], q);
    }
    ps[w][r] = s; pq[w][r] = q;
    __syncthreads();
    float st = ps[0][r] + ps[1][r] + ps[2][r] + ps[3][r];
    float qt = pq[0][r] + pq[1][r] + pq[2][r] + pq[3][r];
    float mu = st / 72.0f;
    float var = fmaxf(qt / 72.0f - mu * mu, 0.0f);
    float rstd = 1.0f / sqrtf(var + 1e-5f);
    float* hw = h + rowid * 72 + o0;
#pragma unroll
    for (int o = 0; o < 18; ++o) hw[o] = (acc[o] - mu) * rstd * g[o0 + o] + beta[o0 + o];
}

// ---------------------------------------------------------------- masked mean-pool + static emb + 2-layer MLP
__global__ void k_head(const float* __restrict__ h, const int* __restrict__ lengths,
                       const float* __restrict__ statics, const float* __restrict__ W_emb,
                       const float* __restrict__ b_emb, const float* __restrict__ w1,
                       const float* __restrict__ bb1, const float* __restrict__ w2,
                       const float* __restrict__ bb2, float* __restrict__ out) {
    __shared__ float ps2[4][72];
    __shared__ float feat[108];
    __shared__ float hidm[108];
    __shared__ float st[9];
    int b = blockIdx.x, tid = threadIdx.x;
    int w = tid >> 6, lane = tid & 63;
    int len = lengths[b];
    if (tid < 9) st[tid] = statics[b * 9 + tid];
    for (int idx = tid; idx < 288; idx += 256) ((float*)ps2)[idx] = 0.f;
    __syncthreads();
#pragma unroll
    for (int c0 = 0; c0 < 128; c0 += 64) {
        int col = c0 + lane;
        if (col < 72) {
            float s = 0.f;
            for (int t = w; t < len; t += 4) s += h[((size_t)t * BB + b) * 72 + col];
            ps2[w][col] = s;
        }
    }
    __syncthreads();
    if (tid < 72)
        feat[tid] = (ps2[0][tid] + ps2[1][tid] + ps2[2][tid] + ps2[3][tid]) / ((float)len + 1.0f);
    if (tid >= 128 && tid < 164) {
        int o = tid - 128;
        float a = b_emb[o];
#pragma unroll
        for (int i = 0; i < 9; ++i) a = fmaf(st[i], W_emb[o * 9 + i], a);
        feat[72 + o] = a;
    }
    __syncthreads();
    if (tid < 108) {
        float a = bb1[tid];
        for (int i = 0; i < 108; ++i) a = fmaf(feat[i], w1[tid * 108 + i], a);
        hidm[tid] = fmaxf(a, 0.f);
    }
    __syncthreads();
    if (tid < 2) {
        float a = bb2[tid];
        for (int i = 0; i < 108; ++i) a = fmaf(hidm[i], w2[tid * 108 + i], a);
        out[b * 2 + tid] = a;
    }
}

// ---------------------------------------------------------------- final distance reduce
__global__ void k_dist(const float* __restrict__ rowsum, float* __restrict__ out) {
    __shared__ float red[256];
    int tid = threadIdx.x;
    red[tid] = rowsum[tid];
    __syncthreads();
    for (int s = 128; s > 0; s >>= 1) { if (tid < s) red[tid] += red[tid + s]; __syncthreads(); }
    if (tid == 0) out[2 * BB] = red[0] / 65536.0f;
}

extern "C" void kernel_launch(void* const* d_in, const int* in_sizes, int n_in,
                              void* d_out, int out_size, void* d_ws, size_t ws_size,
                              hipStream_t stream) {
    const float* src     = (const float*)d_in[0];
    const float* statics = (const float*)d_in[1];
    const float* times   = (const float*)d_in[2];
    const int*   lengths = (const int*)d_in[3];
    const float* W_enc = (const float*)d_in[4];  const float* b_enc = (const float*)d_in[5];
    const float* W_emb = (const float*)d_in[6];  const float* b_emb = (const float*)d_in[7];
    const float* Wq = (const float*)d_in[8];     const float* bq = (const float*)d_in[9];
    const float* Wk = (const float*)d_in[10];    const float* bk = (const float*)d_in[11];
    const float* Wv = (const float*)d_in[12];    const float* bv = (const float*)d_in[13];
    const float* Wskip = (const float*)d_in[14]; const float* bskip = (const float*)d_in[15];
    const float* enc_in_w = (const float*)d_in[16];  const float* enc_in_b = (const float*)d_in[17];
    const float* enc_out_w = (const float*)d_in[18]; const float* enc_out_b = (const float*)d_in[19];
    const float* ff1_w = (const float*)d_in[20]; const float* ff1_b = (const float*)d_in[21];
    const float* ff2_w = (const float*)d_in[22]; const float* ff2_b = (const float*)d_in[23];
    const float* ln1_g = (const float*)d_in[24]; const float* ln1_b = (const float*)d_in[25];
    const float* ln2_g = (const float*)d_in[26]; const float* ln2_b = (const float*)d_in[27];
    const float* w1 = (const float*)d_in[28];    const float* bb1 = (const float*)d_in[29];
    const float* w2 = (const float*)d_in[30];    const float* bb2 = (const float*)d_in[31];
    float* out = (float*)d_out;

    float* p = (float*)d_ws;
    float* x    = p; p += (size_t)ROWS * 36;
    float* h    = p; p += (size_t)ROWS * 72;
    float* qkv  = p; p += (size_t)ROWS * 216;
    float* ctx  = p; p += (size_t)ROWS * 72;
    float* qg   = p; p += (size_t)36 * BB * 36;
    float* kg   = p; p += (size_t)36 * BB * 36;
    float* vg   = p; p += (size_t)36 * BB * 36;
    float* Abuf = p; p += (size_t)BB * 1296;
    float* sqv  = p; p += BB;
    float* rsum = p; p += BB;
    float* ts   = p; p += 32;
    float* T_ff2 = p; p += 2 * 9216;

    k_prep<<<72, 256, 0, stream>>>(ff2_w, T_ff2, ts);
    k_enc1<<<dim3(TT, 4), 256, 0, stream>>>(src, W_enc, b_enc, x);
    k_enc2<<<dim3(TT, 4), 256, 0, stream>>>(x, Wskip, bskip, h);
    k_pe<<<(ROWS * 36) / 256, 256, 0, stream>>>(times, ts, h);
    k_graph_qkv<<<dim3(36, 12), 256, 0, stream>>>(x, Wq, bq, Wk, bk, Wv, bv, qg, kg, vg);
    k_graph_attn<<<BB, 128, 0, stream>>>(qg, kg, vg, h, Abuf, sqv);
    k_gram<<<BB, 256, 0, stream>>>(Abuf, sqv, rsum);
    for (int l = 0; l < 2; ++l) {
        k_qkv<<<ROWS / 64, 256, 0, stream>>>(h, enc_in_w + (size_t)l * 216 * 72,
                                             enc_in_b + l * 216, qkv);
        k_attn<<<BB * 4, 128, 0, stream>>>(qkv, lengths, ctx);
        k_outln<<<ROWS / 64, 256, 0, stream>>>(ctx, enc_out_w + (size_t)l * 5184, enc_out_b + l * 72,
                                               ln1_g + l * 72, ln1_b + l * 72, h);
        k_ffln<<<ROWS / 64, 256, 0, stream>>>(ff1_w + (size_t)l * 128 * 72, ff1_b + l * 128,
                                              T_ff2 + (size_t)l * 9216, ff2_b + l * 72,
                                              ln2_g + l * 72, ln2_b + l * 72, h);
    }
    k_head<<<BB, 256, 0, stream>>>(h, lengths, statics, W_emb, b_emb, w1, bb1, w2, bb2, out);
    k_dist<<<1, 256, 0, stream>>>(rsum, out);
}

// Round 9
// 699.708 us; speedup vs baseline: 1.3099x; 1.3099x over previous
//
#include <hip/hip_runtime.h>

#define TT 215
#define BB 256
#define ROWS (TT * BB)  // 55040 = 860 * 64

typedef __attribute__((ext_vector_type(8))) short short8;   // 8 bf16 = 4 VGPRs
typedef __attribute__((ext_vector_type(4))) float f32x4;    // MFMA acc

__device__ __forceinline__ unsigned short f2bf_rn(float x) {
    unsigned int u = __float_as_uint(x);
    u = u + 0x7FFFu + ((u >> 16) & 1u);   // round-to-nearest-even bf16
    return (unsigned short)(u >> 16);
}
__device__ __forceinline__ float bf2f(unsigned short b) {
    return __uint_as_float(((unsigned int)b) << 16);
}

// ---------------------------------------------------------------- one-shot prep: ff2 transpose + timescales
//                                                                  + split-bf16 enc_in_w [2][216][96] (K zero-padded)
__global__ void k_prep(const float* __restrict__ ff2_w, const float* __restrict__ enc_in_w,
                       float* __restrict__ T_ff2, unsigned short* __restrict__ Whi,
                       unsigned short* __restrict__ Wlo, float* __restrict__ ts) {
    int g = blockIdx.x * 256 + threadIdx.x;
    if (g < 18) ts[g] = (float)pow(215.0, (double)g / 17.0);  // matches np float64 215**linspace
    if (g < 2 * 9216) {  // ff2 [2][72][128] -> [2][j][o]
        int l = g / 9216, e = g % 9216;
        int o = e / 128, j = e % 128;
        T_ff2[l * 9216 + j * 72 + o] = ff2_w[g];
    }
    if (g < 2 * 216 * 96) {
        int l = g / (216 * 96), rem = g % (216 * 96);
        int o = rem / 96, k = rem % 96;
        float v = (k < 72) ? enc_in_w[((size_t)l * 216 + o) * 72 + k] : 0.f;
        unsigned short hi = f2bf_rn(v);
        Whi[g] = hi;
        Wlo[g] = f2bf_rn(v - bf2f(hi));
    }
}

// ---------------------------------------------------------------- x = (src[:,:,:36] @ W_enc.T + b)*6 ; grid (215,4)
__global__ __launch_bounds__(256, 1) void k_enc1(const float* __restrict__ src,
                                                 const float* __restrict__ W,
                                                 const float* __restrict__ bias,
                                                 float* __restrict__ x) {
    int row = blockIdx.x * 256 + threadIdx.x;
    int o0 = blockIdx.y * 9;
    float s[36];
    const float4* sv = (const float4*)(src + (size_t)row * 72);
#pragma unroll
    for (int k = 0; k < 9; ++k) {
        float4 v = sv[k];
        s[4 * k] = v.x; s[4 * k + 1] = v.y; s[4 * k + 2] = v.z; s[4 * k + 3] = v.w;
    }
    float* xp = x + (size_t)row * 36 + o0;
#pragma unroll
    for (int o = 0; o < 9; ++o) {
        float a = bias[o0 + o];
        const float* w = W + (size_t)(o0 + o) * 36;
#pragma unroll
        for (int i = 0; i < 36; ++i) a = fmaf(s[i], w[i], a);
        xp[o] = a * 6.0f;
    }
}

// ---------------------------------------------------------------- h[:,:, :36] = x @ Wskip.T + b ; grid (215,4)
__global__ __launch_bounds__(256, 1) void k_enc2(const float* __restrict__ x,
                                                 const float* __restrict__ W,
                                                 const float* __restrict__ bias,
                                                 float* __restrict__ h) {
    int row = blockIdx.x * 256 + threadIdx.x;
    int o0 = blockIdx.y * 9;
    float xr[36];
    const float4* xv = (const float4*)(x + (size_t)row * 36);
#pragma unroll
    for (int k = 0; k < 9; ++k) {
        float4 v = xv[k];
        xr[4 * k] = v.x; xr[4 * k + 1] = v.y; xr[4 * k + 2] = v.z; xr[4 * k + 3] = v.w;
    }
    float* hp = h + (size_t)row * 72 + o0;
#pragma unroll
    for (int o = 0; o < 9; ++o) {
        float a = bias[o0 + o];
        const float* w = W + (size_t)(o0 + o) * 36;
#pragma unroll
        for (int i = 0; i < 36; ++i) a = fmaf(xr[i], w[i], a);
        hp[o] = a;
    }
}

// ---------------------------------------------------------------- h[:,:,36:] = pe ; elementwise
__global__ __launch_bounds__(256) void k_pe(const float* __restrict__ times,
                                            const float* __restrict__ ts,
                                            float* __restrict__ h) {
    int idx = blockIdx.x * 256 + threadIdx.x;  // < ROWS*36
    int d = idx % 36, row = idx / 36;
    float t = times[row];
    float val;
    if (d < 18) val = sinf(t / ts[d]);
    else        val = cosf(t / ts[d - 18]);
    h[(size_t)row * 72 + 36 + d] = val;
}

// ---------------------------------------------------------------- graph q|k|v ; grid (36, 12): mat = y>>2, o0 = (y&3)*9
__global__ __launch_bounds__(256, 1) void k_graph_qkv(const float* __restrict__ x,
                                                      const float* __restrict__ Wq, const float* __restrict__ bq,
                                                      const float* __restrict__ Wk, const float* __restrict__ bk,
                                                      const float* __restrict__ Wv, const float* __restrict__ bv,
                                                      float* __restrict__ qg, float* __restrict__ kg,
                                                      float* __restrict__ vg) {
    int row = blockIdx.x * 256 + threadIdx.x;  // < 9216
    int mat = blockIdx.y >> 2;
    int o0 = (blockIdx.y & 3) * 9;
    const float* W; const float* bias; float* out;
    if (mat == 0)      { W = Wq; bias = bq; out = qg; }
    else if (mat == 1) { W = Wk; bias = bk; out = kg; }
    else               { W = Wv; bias = bv; out = vg; }
    float xr[36];
    const float4* xv = (const float4*)(x + (size_t)row * 36);
#pragma unroll
    for (int k = 0; k < 9; ++k) {
        float4 v = xv[k];
        xr[4 * k] = v.x; xr[4 * k + 1] = v.y; xr[4 * k + 2] = v.z; xr[4 * k + 3] = v.w;
    }
    float* op = out + (size_t)row * 36 + o0;
#pragma unroll
    for (int o = 0; o < 9; ++o) {
        float a = bias[o0 + o];
        const float* w = W + (size_t)(o0 + o) * 36;
#pragma unroll
        for (int i = 0; i < 36; ++i) a = fmaf(xr[i], w[i], a);
        op[o] = a;
    }
}

// ---------------------------------------------------------------- graph attention per batch; h[:36,:,:36] += msg
__global__ void k_graph_attn(const float* __restrict__ qg, const float* __restrict__ kg,
                             const float* __restrict__ vg, float* __restrict__ h,
                             float* __restrict__ Abuf, float* __restrict__ sqv) {
    __shared__ float q[1296], k[1296], v[1296], A[1296];
    __shared__ float red[128];
    int b = blockIdx.x, tid = threadIdx.x;
    for (int i = tid; i < 1296; i += 128) {
        int t = i / 36, e = i % 36;
        int g = (t * BB + b) * 36 + e;
        q[i] = qg[g]; k[i] = kg[g]; v[i] = vg[g];
    }
    __syncthreads();
    for (int i = tid; i < 1296; i += 128) {
        int r = i / 36, c = i % 36;
        float a = 0.f;
#pragma unroll
        for (int e = 0; e < 36; ++e) a = fmaf(q[r * 36 + e], k[c * 36 + e], a);
        A[i] = a * (1.0f / 6.0f);
    }
    __syncthreads();
    if (tid < 36) {
        float m = -1e30f;
        for (int j = 0; j < 36; ++j) m = fmaxf(m, A[tid * 36 + j]);
        float s = 0.f;
        for (int j = 0; j < 36; ++j) { float e = expf(A[tid * 36 + j] - m); A[tid * 36 + j] = e; s += e; }
        float inv = 1.0f / s;
        for (int j = 0; j < 36; ++j) A[tid * 36 + j] *= inv;
    }
    __syncthreads();
    float lsq = 0.f;
    for (int i = tid; i < 1296; i += 128) {
        float a = A[i];
        Abuf[(size_t)b * 1296 + i] = a;
        lsq = fmaf(a, a, lsq);
        int r = i / 36, e = i % 36;
        float m = 0.f;
#pragma unroll
        for (int j = 0; j < 36; ++j) m = fmaf(A[r * 36 + j], v[j * 36 + e], m);
        h[((size_t)r * BB + b) * 72 + e] += m;
    }
    red[tid] = lsq;
    __syncthreads();
    for (int s = 64; s > 0; s >>= 1) { if (tid < s) red[tid] += red[tid + s]; __syncthreads(); }
    if (tid == 0) sqv[b] = red[0];
}

// ---------------------------------------------------------------- Gram row + per-row distance partial sum
__global__ void k_gram(const float* __restrict__ Abuf, const float* __restrict__ sqv,
                       float* __restrict__ rowsum) {
    __shared__ float Arow[1296];
    __shared__ float red[256];
    int b1 = blockIdx.x, tid = threadIdx.x;
    for (int i = tid; i < 1296; i += 256) Arow[i] = Abuf[(size_t)b1 * 1296 + i];
    __syncthreads();
    int b2 = tid;
    const float* a2 = Abuf + (size_t)b2 * 1296;
    float dot = 0.f;
    for (int e = 0; e < 1296; ++e) dot = fmaf(Arow[e], a2[e], dot);
    float d2 = fmaxf(sqv[b1] + sqv[b2] - 2.0f * dot, 0.0f);
    red[tid] = (d2 > 0.0f) ? sqrtf(d2) : 0.0f;
    __syncthreads();
    for (int s = 128; s > 0; s >>= 1) { if (tid < s) red[tid] += red[tid + s]; __syncthreads(); }
    if (tid == 0) rowsum[b1] = red[0];
}

// ---------------------------------------------------------------- qkv = h @ W_in.T + b ; MFMA split-bf16
// Wave = 16 rows; block = 64 rows. A: m=lane&15, k=quad*8+j. B(pre-split
// bf16 [216][96]): n=lane&15, k=quad*8+j. C/D: col=lane&15, row=quad*4+reg.
// 3 passes (hi*hi + hi*lo + lo*hi) recover fp32 accuracy (drop lo*lo ~1e-5).
__global__ __launch_bounds__(256, 1) void k_qkv(const float* __restrict__ h,
                                                const unsigned short* __restrict__ Whi,
                                                const unsigned short* __restrict__ Wlo,
                                                const float* __restrict__ bias,
                                                float* __restrict__ qkv) {
    int tid = threadIdx.x;
    int w = tid >> 6;
    int lane = tid & 63;
    int n16 = lane & 15;
    int quad = lane >> 4;
    int m0 = blockIdx.x * 64 + w * 16;
    int r = m0 + n16;  // this lane's A row
    // ---- A fragments (3 k-steps of 32, K=72 zero-padded to 96)
    short8 Ahi[3], Alo[3];
#pragma unroll
    for (int s = 0; s < 3; ++s) {
        int k0 = s * 32 + quad * 8;
        float v[8];
        if (k0 < 72) {  // contiguous 8 floats, 32B-aligned
            const float4* ap = (const float4*)(h + (size_t)r * 72 + k0);
            float4 v0 = ap[0], v1 = ap[1];
            v[0] = v0.x; v[1] = v0.y; v[2] = v0.z; v[3] = v0.w;
            v[4] = v1.x; v[5] = v1.y; v[6] = v1.z; v[7] = v1.w;
        } else {
#pragma unroll
            for (int j = 0; j < 8; ++j) v[j] = 0.f;
        }
        short8 ph, pl;
#pragma unroll
        for (int j = 0; j < 8; ++j) {
            unsigned short hi = f2bf_rn(v[j]);
            ph[j] = (short)hi;
            pl[j] = (short)f2bf_rn(v[j] - bf2f(hi));
        }
        Ahi[s] = ph; Alo[s] = pl;
    }
    // ---- N loop: 14 tiles of 16 (last tile: cols 208..215 valid)
    f32x4 acc[14];
#pragma unroll
    for (int t = 0; t < 14; ++t) acc[t] = (f32x4){0.f, 0.f, 0.f, 0.f};
#pragma unroll
    for (int t = 0; t < 14; ++t) {
        int o = t * 16 + n16;
        int oc = (o > 215) ? 215 : o;
        const short8* bh = (const short8*)(Whi + (size_t)oc * 96);
        const short8* bl = (const short8*)(Wlo + (size_t)oc * 96);
        f32x4 a = acc[t];
#pragma unroll
        for (int s = 0; s < 3; ++s) {
            short8 Bh = bh[s * 4 + quad];
            short8 Bl = bl[s * 4 + quad];
            a = __builtin_amdgcn_mfma_f32_16x16x32_bf16(Ahi[s], Bh, a, 0, 0, 0);
            a = __builtin_amdgcn_mfma_f32_16x16x32_bf16(Ahi[s], Bl, a, 0, 0, 0);
            a = __builtin_amdgcn_mfma_f32_16x16x32_bf16(Alo[s], Bh, a, 0, 0, 0);
        }
        acc[t] = a;
    }
    // ---- epilogue: bias + store (C/D layout)
#pragma unroll
    for (int t = 0; t < 14; ++t) {
        int col = t * 16 + n16;
        if (col < 216) {
            float b = bias[col];
#pragma unroll
            for (int reg = 0; reg < 4; ++reg) {
                int row = m0 + quad * 4 + reg;
                qkv[(size_t)row * 216 + col] = acc[t][reg] + b;
            }
        }
    }
}

// ---------------------------------------------------------------- masked MHA, block = (b, head), 128 thr, 2 queries/lane
__global__ __launch_bounds__(128, 1) void k_attn(const float* __restrict__ qkv,
                                                 const int* __restrict__ lengths,
                                                 float* __restrict__ ctx) {
    __shared__ float Ks[TT * 20];
    __shared__ float Vs[TT * 20];
    int b = blockIdx.x & (BB - 1);
    int hh = blockIdx.x >> 8;
    int tid = threadIdx.x;
    int len = lengths[b];
    int n20 = len * 20;  // only stage valid keys
    for (int i = tid; i < n20; i += 128) {
        int s = i / 20, d = i % 20;
        float kk = 0.f, vv = 0.f;
        if (d < 18) {
            size_t base2 = ((size_t)s * BB + b) * 216 + hh * 18 + d;
            kk = qkv[base2 + 72];
            vv = qkv[base2 + 144];
        }
        Ks[i] = kk; Vs[i] = vv;
    }
    __syncthreads();
    int t0 = tid, t1 = tid + 128;
    bool two = (t1 < TT);
    const float scale = 0.23570226039551587f;  // 1/sqrt(18); folded into q
    float q0[20], q1[20];
    q0[18] = q0[19] = q1[18] = q1[19] = 0.f;
    {
        const float* qb = qkv + ((size_t)t0 * BB + b) * 216 + hh * 18;
#pragma unroll
        for (int d = 0; d < 18; ++d) q0[d] = qb[d] * scale;
    }
    if (two) {
        const float* qb = qkv + ((size_t)t1 * BB + b) * 216 + hh * 18;
#pragma unroll
        for (int d = 0; d < 18; ++d) q1[d] = qb[d] * scale;
    } else {
#pragma unroll
        for (int d = 0; d < 18; ++d) q1[d] = 0.f;
    }
    // scores bounded (LN'd activations x 0.05-scale weights): exp cannot overflow -> skip online max
    float l0 = 0.f, l1 = 0.f;
    float acc0[20], acc1[20];
#pragma unroll
    for (int d = 0; d < 20; ++d) { acc0[d] = 0.f; acc1[d] = 0.f; }
    const float4* kp = (const float4*)Ks;
    const float4* vp = (const float4*)Vs;
    for (int s = 0; s < len; ++s) {
        float sc0 = 0.f, sc1 = 0.f;
#pragma unroll
        for (int c = 0; c < 5; ++c) {
            float4 kv = kp[s * 5 + c];
            sc0 = fmaf(q0[4 * c], kv.x, sc0); sc1 = fmaf(q1[4 * c], kv.x, sc1);
            sc0 = fmaf(q0[4 * c + 1], kv.y, sc0); sc1 = fmaf(q1[4 * c + 1], kv.y, sc1);
            sc0 = fmaf(q0[4 * c + 2], kv.z, sc0); sc1 = fmaf(q1[4 * c + 2], kv.z, sc1);
            sc0 = fmaf(q0[4 * c + 3], kv.w, sc0); sc1 = fmaf(q1[4 * c + 3], kv.w, sc1);
        }
        float p0 = __expf(sc0), p1 = __expf(sc1);
        l0 += p0; l1 += p1;
#pragma unroll
        for (int c = 0; c < 5; ++c) {
            float4 vv = vp[s * 5 + c];
            acc0[4 * c]     = fmaf(p0, vv.x, acc0[4 * c]);
            acc0[4 * c + 1] = fmaf(p0, vv.y, acc0[4 * c + 1]);
            acc0[4 * c + 2] = fmaf(p0, vv.z, acc0[4 * c + 2]);
            acc0[4 * c + 3] = fmaf(p0, vv.w, acc0[4 * c + 3]);
            acc1[4 * c]     = fmaf(p1, vv.x, acc1[4 * c]);
            acc1[4 * c + 1] = fmaf(p1, vv.y, acc1[4 * c + 1]);
            acc1[4 * c + 2] = fmaf(p1, vv.z, acc1[4 * c + 2]);
            acc1[4 * c + 3] = fmaf(p1, vv.w, acc1[4 * c + 3]);
        }
    }
    {
        float inv = 1.0f / l0;
        float* cb = ctx + ((size_t)t0 * BB + b) * 72 + hh * 18;
#pragma unroll
        for (int d = 0; d < 18; ++d) cb[d] = acc0[d] * inv;
    }
    if (two) {
        float inv = 1.0f / l1;
        float* cb = ctx + ((size_t)t1 * BB + b) * 72 + hh * 18;
#pragma unroll
        for (int d = 0; d < 18; ++d) cb[d] = acc1[d] * inv;
    }
}

// ---------------------------------------------------------------- h = LN(h + ctx@Wout.T+b) ; 64 rows x 4 out-waves
__global__ __launch_bounds__(256, 1) void k_outln(const float* __restrict__ ctx,
                                                  const float* __restrict__ W,
                                                  const float* __restrict__ bias,
                                                  const float* __restrict__ g,
                                                  const float* __restrict__ beta,
                                                  float* __restrict__ h) {
    __shared__ float ps[4][64], pq[4][64];
    int tid = threadIdx.x;
    int w = __builtin_amdgcn_readfirstlane(tid >> 6);  // wave-uniform -> s_load weights
    int r = tid & 63;
    size_t rowid = (size_t)blockIdx.x * 64 + r;
    int o0 = w * 18;
    float cr[72];
    const float4* cv = (const float4*)(ctx + rowid * 72);
#pragma unroll
    for (int k = 0; k < 18; ++k) {
        float4 v = cv[k];
        cr[4 * k] = v.x; cr[4 * k + 1] = v.y; cr[4 * k + 2] = v.z; cr[4 * k + 3] = v.w;
    }
    float acc[18];
#pragma unroll
    for (int oo = 0; oo < 18; oo += 3) {
        int j0 = o0 + oo;
        float a0 = bias[j0], a1 = bias[j0 + 1], a2 = bias[j0 + 2];
        const float* w0 = W + (size_t)j0 * 72;
#pragma unroll
        for (int i = 0; i < 72; ++i) {
            a0 = fmaf(cr[i], w0[i], a0);
            a1 = fmaf(cr[i], w0[72 + i], a1);
            a2 = fmaf(cr[i], w0[144 + i], a2);
        }
        acc[oo] = a0; acc[oo + 1] = a1; acc[oo + 2] = a2;
    }
    const float* hres = h + rowid * 72 + o0;
    float s = 0.f, q = 0.f;
#pragma unroll
    for (int o = 0; o < 18; ++o) {
        acc[o] += hres[o];
        s += acc[o];
        q = fmaf(acc[o], acc[o], q);
    }
    ps[w][r] = s; pq[w][r] = q;
    __syncthreads();
    float st = ps[0][r] + ps[1][r] + ps[2][r] + ps[3][r];
    float qt = pq[0][r] + pq[1][r] + pq[2][r] + pq[3][r];
    float mu = st / 72.0f;
    float var = fmaxf(qt / 72.0f - mu * mu, 0.0f);
    float rstd = 1.0f / sqrtf(var + 1e-5f);
    float* hw = h + rowid * 72 + o0;
#pragma unroll
    for (int o = 0; o < 18; ++o) hw[o] = (acc[o] - mu) * rstd * g[o0 + o] + beta[o0 + o];
}

// ---------------------------------------------------------------- h = LN(h + relu(h@ff1.T)@ff2.T+b) ; 64 rows x 4 waves
__global__ __launch_bounds__(256, 1) void k_ffln(const float* __restrict__ ff1,
                                                 const float* __restrict__ b1,
                                                 const float* __restrict__ Tff2,
                                                 const float* __restrict__ b2,
                                                 const float* __restrict__ g,
                                                 const float* __restrict__ beta,
                                                 float* __restrict__ h) {
    __shared__ float hid[64][129];  // bank = (r + j) % 32: conflict-free
    __shared__ float ps[4][64], pq[4][64];
    int tid = threadIdx.x;
    int w = __builtin_amdgcn_readfirstlane(tid >> 6);  // wave-uniform -> s_load weights
    int r = tid & 63;
    size_t rowid = (size_t)blockIdx.x * 64 + r;
    float hr[72];
    const float4* hv = (const float4*)(h + rowid * 72);
#pragma unroll
    for (int k = 0; k < 18; ++k) {
        float4 v = hv[k];
        hr[4 * k] = v.x; hr[4 * k + 1] = v.y; hr[4 * k + 2] = v.z; hr[4 * k + 3] = v.w;
    }
    int j0 = w * 32;
    for (int jj = 0; jj < 32; jj += 2) {
        int j = j0 + jj;
        float a0 = b1[j], a1 = b1[j + 1];
        const float* wp = ff1 + (size_t)j * 72;
#pragma unroll
        for (int i = 0; i < 72; ++i) {
            a0 = fmaf(hr[i], wp[i], a0);
            a1 = fmaf(hr[i], wp[72 + i], a1);
        }
        hid[r][j] = fmaxf(a0, 0.f);
        hid[r][j + 1] = fmaxf(a1, 0.f);
    }
    __syncthreads();
    int o0 = w * 18;
    float acc[18];
#pragma unroll
    for (int o = 0; o < 18; ++o) acc[o] = b2[o0 + o];
    for (int j = 0; j < 128; ++j) {
        float hj = hid[r][j];
        const float* wt = Tff2 + (size_t)j * 72 + o0;
#pragma unroll
        for (int o = 0; o < 18; ++o) acc[o] = fmaf(hj, wt[o], acc[o]);
    }
    const float* hres = h + rowid * 72 + o0;
    float s = 0.f, q = 0.f;
#pragma unroll
    for (int o = 0; o < 18; ++o) {
        acc[o] += hres[o];
        s += acc[o];
        q = fmaf(acc[o], acc[o], q);
    }
    ps[w][r] = s; pq[w][r] = q;
    __syncthreads();
    float st = ps[0][r] + ps[1][r] + ps[2][r] + ps[3][r];
    float qt = pq[0][r] + pq[1][r] + pq[2][r] + pq[3][r];
    float mu = st / 72.0f;
    float var = fmaxf(qt / 72.0f - mu * mu, 0.0f);
    float rstd = 1.0f / sqrtf(var + 1e-5f);
    float* hw = h + rowid * 72 + o0;
#pragma unroll
    for (int o = 0; o < 18; ++o) hw[o] = (acc[o] - mu) * rstd * g[o0 + o] + beta[o0 + o];
}

// ---------------------------------------------------------------- masked mean-pool + static emb + 2-layer MLP
__global__ void k_head(const float* __restrict__ h, const int* __restrict__ lengths,
                       const float* __restrict__ statics, const float* __restrict__ W_emb,
                       const float* __restrict__ b_emb, const float* __restrict__ w1,
                       const float* __restrict__ bb1, const float* __restrict__ w2,
                       const float* __restrict__ bb2, float* __restrict__ out) {
    __shared__ float ps2[4][72];
    __shared__ float feat[108];
    __shared__ float hidm[108];
    __shared__ float st[9];
    int b = blockIdx.x, tid = threadIdx.x;
    int w = tid >> 6, lane = tid & 63;
    int len = lengths[b];
    if (tid < 9) st[tid] = statics[b * 9 + tid];
    for (int idx = tid; idx < 288; idx += 256) ((float*)ps2)[idx] = 0.f;
    __syncthreads();
#pragma unroll
    for (int c0 = 0; c0 < 128; c0 += 64) {
        int col = c0 + lane;
        if (col < 72) {
            float s = 0.f;
            for (int t = w; t < len; t += 4) s += h[((size_t)t * BB + b) * 72 + col];
            ps2[w][col] = s;
        }
    }
    __syncthreads();
    if (tid < 72)
        feat[tid] = (ps2[0][tid] + ps2[1][tid] + ps2[2][tid] + ps2[3][tid]) / ((float)len + 1.0f);
    if (tid >= 128 && tid < 164) {
        int o = tid - 128;
        float a = b_emb[o];
#pragma unroll
        for (int i = 0; i < 9; ++i) a = fmaf(st[i], W_emb[o * 9 + i], a);
        feat[72 + o] = a;
    }
    __syncthreads();
    if (tid < 108) {
        float a = bb1[tid];
        for (int i = 0; i < 108; ++i) a = fmaf(feat[i], w1[tid * 108 + i], a);
        hidm[tid] = fmaxf(a, 0.f);
    }
    __syncthreads();
    if (tid < 2) {
        float a = bb2[tid];
        for (int i = 0; i < 108; ++i) a = fmaf(hidm[i], w2[tid * 108 + i], a);
        out[b * 2 + tid] = a;
    }
}

// ---------------------------------------------------------------- final distance reduce
__global__ void k_dist(const float* __restrict__ rowsum, float* __restrict__ out) {
    __shared__ float red[256];
    int tid = threadIdx.x;
    red[tid] = rowsum[tid];
    __syncthreads();
    for (int s = 128; s > 0; s >>= 1) { if (tid < s) red[tid] += red[tid + s]; __syncthreads(); }
    if (tid == 0) out[2 * BB] = red[0] / 65536.0f;
}

extern "C" void kernel_launch(void* const* d_in, const int* in_sizes, int n_in,
                              void* d_out, int out_size, void* d_ws, size_t ws_size,
                              hipStream_t stream) {
    const float* src     = (const float*)d_in[0];
    const float* statics = (const float*)d_in[1];
    const float* times   = (const float*)d_in[2];
    const int*   lengths = (const int*)d_in[3];
    const float* W_enc = (const float*)d_in[4];  const float* b_enc = (const float*)d_in[5];
    const float* W_emb = (const float*)d_in[6];  const float* b_emb = (const float*)d_in[7];
    const float* Wq = (const float*)d_in[8];     const float* bq = (const float*)d_in[9];
    const float* Wk = (const float*)d_in[10];    const float* bk = (const float*)d_in[11];
    const float* Wv = (const float*)d_in[12];    const float* bv = (const float*)d_in[13];
    const float* Wskip = (const float*)d_in[14]; const float* bskip = (const float*)d_in[15];
    const float* enc_in_w = (const float*)d_in[16];  const float* enc_in_b = (const float*)d_in[17];
    const float* enc_out_w = (const float*)d_in[18]; const float* enc_out_b = (const float*)d_in[19];
    const float* ff1_w = (const float*)d_in[20]; const float* ff1_b = (const float*)d_in[21];
    const float* ff2_w = (const float*)d_in[22]; const float* ff2_b = (const float*)d_in[23];
    const float* ln1_g = (const float*)d_in[24]; const float* ln1_b = (const float*)d_in[25];
    const float* ln2_g = (const float*)d_in[26]; const float* ln2_b = (const float*)d_in[27];
    const float* w1 = (const float*)d_in[28];    const float* bb1 = (const float*)d_in[29];
    const float* w2 = (const float*)d_in[30];    const float* bb2 = (const float*)d_in[31];
    float* out = (float*)d_out;

    float* p = (float*)d_ws;
    float* x    = p; p += (size_t)ROWS * 36;
    float* h    = p; p += (size_t)ROWS * 72;
    float* qkv  = p; p += (size_t)ROWS * 216;
    float* ctx  = p; p += (size_t)ROWS * 72;
    float* qg   = p; p += (size_t)36 * BB * 36;
    float* kg   = p; p += (size_t)36 * BB * 36;
    float* vg   = p; p += (size_t)36 * BB * 36;
    float* Abuf = p; p += (size_t)BB * 1296;
    float* sqv  = p; p += BB;
    float* rsum = p; p += BB;
    float* ts   = p; p += 32;
    float* T_ff2 = p; p += 2 * 9216;
    unsigned short* Whi = (unsigned short*)p; p += (2 * 216 * 96) / 2;   // bf16 hi, [2][216][96]
    unsigned short* Wlo = (unsigned short*)p; p += (2 * 216 * 96) / 2;   // bf16 lo

    k_prep<<<162, 256, 0, stream>>>(ff2_w, enc_in_w, T_ff2, Whi, Wlo, ts);
    k_enc1<<<dim3(TT, 4), 256, 0, stream>>>(src, W_enc, b_enc, x);
    k_enc2<<<dim3(TT, 4), 256, 0, stream>>>(x, Wskip, bskip, h);
    k_pe<<<(ROWS * 36) / 256, 256, 0, stream>>>(times, ts, h);
    k_graph_qkv<<<dim3(36, 12), 256, 0, stream>>>(x, Wq, bq, Wk, bk, Wv, bv, qg, kg, vg);
    k_graph_attn<<<BB, 128, 0, stream>>>(qg, kg, vg, h, Abuf, sqv);
    k_gram<<<BB, 256, 0, stream>>>(Abuf, sqv, rsum);
    for (int l = 0; l < 2; ++l) {
        k_qkv<<<ROWS / 64, 256, 0, stream>>>(h, Whi + (size_t)l * 216 * 96,
                                             Wlo + (size_t)l * 216 * 96,
                                             enc_in_b + l * 216, qkv);
        k_attn<<<BB * 4, 128, 0, stream>>>(qkv, lengths, ctx);
        k_outln<<<ROWS / 64, 256, 0, stream>>>(ctx, enc_out_w + (size_t)l * 5184, enc_out_b + l * 72,
                                               ln1_g + l * 72, ln1_b + l * 72, h);
        k_ffln<<<ROWS / 64, 256, 0, stream>>>(ff1_w + (size_t)l * 128 * 72, ff1_b + l * 128,
                                              T_ff2 + (size_t)l * 9216, ff2_b + l * 72,
                                              ln2_g + l * 72, ln2_b + l * 72, h);
    }
    k_head<<<BB, 256, 0, stream>>>(h, lengths, statics, W_emb, b_emb, w1, bb1, w2, bb2, out);
    k_dist<<<1, 256, 0, stream>>>(rsum, out);
}

// Round 10
// 574.070 us; speedup vs baseline: 1.5966x; 1.2189x over previous
//
#include <hip/hip_runtime.h>

#define TT 215
#define BB 256
#define ROWS (TT * BB)  // 55040 = 860 * 64

typedef __attribute__((ext_vector_type(8))) short short8;   // 8 bf16 = 4 VGPRs
typedef __attribute__((ext_vector_type(4))) float f32x4;    // MFMA acc

__device__ __forceinline__ unsigned short f2bf_rn(float x) {
    unsigned int u = __float_as_uint(x);
    u = u + 0x7FFFu + ((u >> 16) & 1u);   // round-to-nearest-even bf16
    return (unsigned short)(u >> 16);
}
__device__ __forceinline__ float bf2f(unsigned short b) {
    return __uint_as_float(((unsigned int)b) << 16);
}

// ---------------------------------------------------------------- one-shot prep: timescales + split-bf16 weights
// enc_in [2][216][96], ff1 [2][128][96], ff2 [2][72][128], Wout [2][72][96]
__global__ void k_prep(const float* __restrict__ enc_in_w, const float* __restrict__ ff1_w,
                       const float* __restrict__ ff2_w, const float* __restrict__ enc_out_w,
                       unsigned short* __restrict__ Whi, unsigned short* __restrict__ Wlo,
                       unsigned short* __restrict__ F1hi, unsigned short* __restrict__ F1lo,
                       unsigned short* __restrict__ F2hi, unsigned short* __restrict__ F2lo,
                       unsigned short* __restrict__ Ohi, unsigned short* __restrict__ Olo,
                       float* __restrict__ ts) {
    int g = blockIdx.x * 256 + threadIdx.x;
    if (g < 18) ts[g] = (float)pow(215.0, (double)g / 17.0);  // matches np float64 215**linspace
    if (g < 2 * 216 * 96) {
        int l = g / (216 * 96), rem = g % (216 * 96);
        int o = rem / 96, k = rem % 96;
        float v = (k < 72) ? enc_in_w[((size_t)l * 216 + o) * 72 + k] : 0.f;
        unsigned short hi = f2bf_rn(v);
        Whi[g] = hi; Wlo[g] = f2bf_rn(v - bf2f(hi));
    }
    if (g < 2 * 128 * 96) {
        int l = g / (128 * 96), rem = g % (128 * 96);
        int j = rem / 96, k = rem % 96;
        float v = (k < 72) ? ff1_w[((size_t)l * 128 + j) * 72 + k] : 0.f;
        unsigned short hi = f2bf_rn(v);
        F1hi[g] = hi; F1lo[g] = f2bf_rn(v - bf2f(hi));
    }
    if (g < 2 * 72 * 128) {  // ff2 already [o][j] = B[n][k], K=128
        float v = ff2_w[g];
        unsigned short hi = f2bf_rn(v);
        F2hi[g] = hi; F2lo[g] = f2bf_rn(v - bf2f(hi));
    }
    if (g < 2 * 72 * 96) {
        int l = g / (72 * 96), rem = g % (72 * 96);
        int o = rem / 96, k = rem % 96;
        float v = (k < 72) ? enc_out_w[((size_t)l * 72 + o) * 72 + k] : 0.f;
        unsigned short hi = f2bf_rn(v);
        Ohi[g] = hi; Olo[g] = f2bf_rn(v - bf2f(hi));
    }
}

// ---------------------------------------------------------------- x = (src[:,:,:36] @ W_enc.T + b)*6 ; grid (215,4)
__global__ __launch_bounds__(256, 1) void k_enc1(const float* __restrict__ src,
                                                 const float* __restrict__ W,
                                                 const float* __restrict__ bias,
                                                 float* __restrict__ x) {
    int row = blockIdx.x * 256 + threadIdx.x;
    int o0 = blockIdx.y * 9;
    float s[36];
    const float4* sv = (const float4*)(src + (size_t)row * 72);
#pragma unroll
    for (int k = 0; k < 9; ++k) {
        float4 v = sv[k];
        s[4 * k] = v.x; s[4 * k + 1] = v.y; s[4 * k + 2] = v.z; s[4 * k + 3] = v.w;
    }
    float* xp = x + (size_t)row * 36 + o0;
#pragma unroll
    for (int o = 0; o < 9; ++o) {
        float a = bias[o0 + o];
        const float* w = W + (size_t)(o0 + o) * 36;
#pragma unroll
        for (int i = 0; i < 36; ++i) a = fmaf(s[i], w[i], a);
        xp[o] = a * 6.0f;
    }
}

// ---------------------------------------------------------------- h[:,:, :36] = x @ Wskip.T + b ; grid (215,4)
__global__ __launch_bounds__(256, 1) void k_enc2(const float* __restrict__ x,
                                                 const float* __restrict__ W,
                                                 const float* __restrict__ bias,
                                                 float* __restrict__ h) {
    int row = blockIdx.x * 256 + threadIdx.x;
    int o0 = blockIdx.y * 9;
    float xr[36];
    const float4* xv = (const float4*)(x + (size_t)row * 36);
#pragma unroll
    for (int k = 0; k < 9; ++k) {
        float4 v = xv[k];
        xr[4 * k] = v.x; xr[4 * k + 1] = v.y; xr[4 * k + 2] = v.z; xr[4 * k + 3] = v.w;
    }
    float* hp = h + (size_t)row * 72 + o0;
#pragma unroll
    for (int o = 0; o < 9; ++o) {
        float a = bias[o0 + o];
        const float* w = W + (size_t)(o0 + o) * 36;
#pragma unroll
        for (int i = 0; i < 36; ++i) a = fmaf(xr[i], w[i], a);
        hp[o] = a;
    }
}

// ---------------------------------------------------------------- h[:,:,36:] = pe ; elementwise
__global__ __launch_bounds__(256) void k_pe(const float* __restrict__ times,
                                            const float* __restrict__ ts,
                                            float* __restrict__ h) {
    int idx = blockIdx.x * 256 + threadIdx.x;  // < ROWS*36
    int d = idx % 36, row = idx / 36;
    float t = times[row];
    float val;
    if (d < 18) val = sinf(t / ts[d]);
    else        val = cosf(t / ts[d - 18]);
    h[(size_t)row * 72 + 36 + d] = val;
}

// ---------------------------------------------------------------- graph q|k|v ; grid (36, 12): mat = y>>2, o0 = (y&3)*9
__global__ __launch_bounds__(256, 1) void k_graph_qkv(const float* __restrict__ x,
                                                      const float* __restrict__ Wq, const float* __restrict__ bq,
                                                      const float* __restrict__ Wk, const float* __restrict__ bk,
                                                      const float* __restrict__ Wv, const float* __restrict__ bv,
                                                      float* __restrict__ qg, float* __restrict__ kg,
                                                      float* __restrict__ vg) {
    int row = blockIdx.x * 256 + threadIdx.x;  // < 9216
    int mat = blockIdx.y >> 2;
    int o0 = (blockIdx.y & 3) * 9;
    const float* W; const float* bias; float* out;
    if (mat == 0)      { W = Wq; bias = bq; out = qg; }
    else if (mat == 1) { W = Wk; bias = bk; out = kg; }
    else               { W = Wv; bias = bv; out = vg; }
    float xr[36];
    const float4* xv = (const float4*)(x + (size_t)row * 36);
#pragma unroll
    for (int k = 0; k < 9; ++k) {
        float4 v = xv[k];
        xr[4 * k] = v.x; xr[4 * k + 1] = v.y; xr[4 * k + 2] = v.z; xr[4 * k + 3] = v.w;
    }
    float* op = out + (size_t)row * 36 + o0;
#pragma unroll
    for (int o = 0; o < 9; ++o) {
        float a = bias[o0 + o];
        const float* w = W + (size_t)(o0 + o) * 36;
#pragma unroll
        for (int i = 0; i < 36; ++i) a = fmaf(xr[i], w[i], a);
        op[o] = a;
    }
}

// ---------------------------------------------------------------- graph attention per batch; h[:36,:,:36] += msg
__global__ void k_graph_attn(const float* __restrict__ qg, const float* __restrict__ kg,
                             const float* __restrict__ vg, float* __restrict__ h,
                             float* __restrict__ Abuf, float* __restrict__ sqv) {
    __shared__ float q[1296], k[1296], v[1296], A[1296];
    __shared__ float red[128];
    int b = blockIdx.x, tid = threadIdx.x;
    for (int i = tid; i < 1296; i += 128) {
        int t = i / 36, e = i % 36;
        int g = (t * BB + b) * 36 + e;
        q[i] = qg[g]; k[i] = kg[g]; v[i] = vg[g];
    }
    __syncthreads();
    for (int i = tid; i < 1296; i += 128) {
        int r = i / 36, c = i % 36;
        float a = 0.f;
#pragma unroll
        for (int e = 0; e < 36; ++e) a = fmaf(q[r * 36 + e], k[c * 36 + e], a);
        A[i] = a * (1.0f / 6.0f);
    }
    __syncthreads();
    if (tid < 36) {
        float m = -1e30f;
        for (int j = 0; j < 36; ++j) m = fmaxf(m, A[tid * 36 + j]);
        float s = 0.f;
        for (int j = 0; j < 36; ++j) { float e = expf(A[tid * 36 + j] - m); A[tid * 36 + j] = e; s += e; }
        float inv = 1.0f / s;
        for (int j = 0; j < 36; ++j) A[tid * 36 + j] *= inv;
    }
    __syncthreads();
    float lsq = 0.f;
    for (int i = tid; i < 1296; i += 128) {
        float a = A[i];
        Abuf[(size_t)b * 1296 + i] = a;
        lsq = fmaf(a, a, lsq);
        int r = i / 36, e = i % 36;
        float m = 0.f;
#pragma unroll
        for (int j = 0; j < 36; ++j) m = fmaf(A[r * 36 + j], v[j * 36 + e], m);
        h[((size_t)r * BB + b) * 72 + e] += m;
    }
    red[tid] = lsq;
    __syncthreads();
    for (int s = 64; s > 0; s >>= 1) { if (tid < s) red[tid] += red[tid + s]; __syncthreads(); }
    if (tid == 0) sqv[b] = red[0];
}

// ---------------------------------------------------------------- Gram row + per-row distance partial sum
__global__ void k_gram(const float* __restrict__ Abuf, const float* __restrict__ sqv,
                       float* __restrict__ rowsum) {
    __shared__ float Arow[1296];
    __shared__ float red[256];
    int b1 = blockIdx.x, tid = threadIdx.x;
    for (int i = tid; i < 1296; i += 256) Arow[i] = Abuf[(size_t)b1 * 1296 + i];
    __syncthreads();
    int b2 = tid;
    const float* a2 = Abuf + (size_t)b2 * 1296;
    float dot = 0.f;
    for (int e = 0; e < 1296; ++e) dot = fmaf(Arow[e], a2[e], dot);
    float d2 = fmaxf(sqv[b1] + sqv[b2] - 2.0f * dot, 0.0f);
    red[tid] = (d2 > 0.0f) ? sqrtf(d2) : 0.0f;
    __syncthreads();
    for (int s = 128; s > 0; s >>= 1) { if (tid < s) red[tid] += red[tid + s]; __syncthreads(); }
    if (tid == 0) rowsum[b1] = red[0];
}

// ---------------------------------------------------------------- qkv = h @ W_in.T + b ; MFMA split-bf16
__global__ __launch_bounds__(256, 1) void k_qkv(const float* __restrict__ h,
                                                const unsigned short* __restrict__ Whi,
                                                const unsigned short* __restrict__ Wlo,
                                                const float* __restrict__ bias,
                                                float* __restrict__ qkv) {
    int tid = threadIdx.x;
    int w = tid >> 6;
    int lane = tid & 63;
    int n16 = lane & 15;
    int quad = lane >> 4;
    int m0 = blockIdx.x * 64 + w * 16;
    int r = m0 + n16;
    short8 Ahi[3], Alo[3];
#pragma unroll
    for (int s = 0; s < 3; ++s) {
        int k0 = s * 32 + quad * 8;
        float v[8];
        if (k0 < 72) {
            const float4* ap = (const float4*)(h + (size_t)r * 72 + k0);
            float4 v0 = ap[0], v1 = ap[1];
            v[0] = v0.x; v[1] = v0.y; v[2] = v0.z; v[3] = v0.w;
            v[4] = v1.x; v[5] = v1.y; v[6] = v1.z; v[7] = v1.w;
        } else {
#pragma unroll
            for (int j = 0; j < 8; ++j) v[j] = 0.f;
        }
        short8 ph, pl;
#pragma unroll
        for (int j = 0; j < 8; ++j) {
            unsigned short hi = f2bf_rn(v[j]);
            ph[j] = (short)hi;
            pl[j] = (short)f2bf_rn(v[j] - bf2f(hi));
        }
        Ahi[s] = ph; Alo[s] = pl;
    }
    f32x4 acc[14];
#pragma unroll
    for (int t = 0; t < 14; ++t) acc[t] = (f32x4){0.f, 0.f, 0.f, 0.f};
#pragma unroll
    for (int t = 0; t < 14; ++t) {
        int o = t * 16 + n16;
        int oc = (o > 215) ? 215 : o;
        const short8* bh = (const short8*)(Whi + (size_t)oc * 96);
        const short8* bl = (const short8*)(Wlo + (size_t)oc * 96);
        f32x4 a = acc[t];
#pragma unroll
        for (int s = 0; s < 3; ++s) {
            short8 Bh = bh[s * 4 + quad];
            short8 Bl = bl[s * 4 + quad];
            a = __builtin_amdgcn_mfma_f32_16x16x32_bf16(Ahi[s], Bh, a, 0, 0, 0);
            a = __builtin_amdgcn_mfma_f32_16x16x32_bf16(Ahi[s], Bl, a, 0, 0, 0);
            a = __builtin_amdgcn_mfma_f32_16x16x32_bf16(Alo[s], Bh, a, 0, 0, 0);
        }
        acc[t] = a;
    }
#pragma unroll
    for (int t = 0; t < 14; ++t) {
        int col = t * 16 + n16;
        if (col < 216) {
            float b = bias[col];
#pragma unroll
            for (int reg = 0; reg < 4; ++reg) {
                int row = m0 + quad * 4 + reg;
                qkv[(size_t)row * 216 + col] = acc[t][reg] + b;
            }
        }
    }
}

// ---------------------------------------------------------------- masked MHA, block = (b, head), 128 thr, 2 queries/lane
__global__ __launch_bounds__(128, 1) void k_attn(const float* __restrict__ qkv,
                                                 const int* __restrict__ lengths,
                                                 float* __restrict__ ctx) {
    __shared__ float Ks[TT * 20];
    __shared__ float Vs[TT * 20];
    int b = blockIdx.x & (BB - 1);
    int hh = blockIdx.x >> 8;
    int tid = threadIdx.x;
    int len = lengths[b];
    int n20 = len * 20;  // only stage valid keys
    for (int i = tid; i < n20; i += 128) {
        int s = i / 20, d = i % 20;
        float kk = 0.f, vv = 0.f;
        if (d < 18) {
            size_t base2 = ((size_t)s * BB + b) * 216 + hh * 18 + d;
            kk = qkv[base2 + 72];
            vv = qkv[base2 + 144];
        }
        Ks[i] = kk; Vs[i] = vv;
    }
    __syncthreads();
    int t0 = tid, t1 = tid + 128;
    bool two = (t1 < TT);
    const float scale = 0.23570226039551587f;  // 1/sqrt(18); folded into q
    float q0[20], q1[20];
    q0[18] = q0[19] = q1[18] = q1[19] = 0.f;
    {
        const float* qb = qkv + ((size_t)t0 * BB + b) * 216 + hh * 18;
#pragma unroll
        for (int d = 0; d < 18; ++d) q0[d] = qb[d] * scale;
    }
    if (two) {
        const float* qb = qkv + ((size_t)t1 * BB + b) * 216 + hh * 18;
#pragma unroll
        for (int d = 0; d < 18; ++d) q1[d] = qb[d] * scale;
    } else {
#pragma unroll
        for (int d = 0; d < 18; ++d) q1[d] = 0.f;
    }
    float l0 = 0.f, l1 = 0.f;
    float acc0[20], acc1[20];
#pragma unroll
    for (int d = 0; d < 20; ++d) { acc0[d] = 0.f; acc1[d] = 0.f; }
    const float4* kp = (const float4*)Ks;
    const float4* vp = (const float4*)Vs;
    for (int s = 0; s < len; ++s) {
        float sc0 = 0.f, sc1 = 0.f;
#pragma unroll
        for (int c = 0; c < 5; ++c) {
            float4 kv = kp[s * 5 + c];
            sc0 = fmaf(q0[4 * c], kv.x, sc0); sc1 = fmaf(q1[4 * c], kv.x, sc1);
            sc0 = fmaf(q0[4 * c + 1], kv.y, sc0); sc1 = fmaf(q1[4 * c + 1], kv.y, sc1);
            sc0 = fmaf(q0[4 * c + 2], kv.z, sc0); sc1 = fmaf(q1[4 * c + 2], kv.z, sc1);
            sc0 = fmaf(q0[4 * c + 3], kv.w, sc0); sc1 = fmaf(q1[4 * c + 3], kv.w, sc1);
        }
        float p0 = __expf(sc0), p1 = __expf(sc1);
        l0 += p0; l1 += p1;
#pragma unroll
        for (int c = 0; c < 5; ++c) {
            float4 vv = vp[s * 5 + c];
            acc0[4 * c]     = fmaf(p0, vv.x, acc0[4 * c]);
            acc0[4 * c + 1] = fmaf(p0, vv.y, acc0[4 * c + 1]);
            acc0[4 * c + 2] = fmaf(p0, vv.z, acc0[4 * c + 2]);
            acc0[4 * c + 3] = fmaf(p0, vv.w, acc0[4 * c + 3]);
            acc1[4 * c]     = fmaf(p1, vv.x, acc1[4 * c]);
            acc1[4 * c + 1] = fmaf(p1, vv.y, acc1[4 * c + 1]);
            acc1[4 * c + 2] = fmaf(p1, vv.z, acc1[4 * c + 2]);
            acc1[4 * c + 3] = fmaf(p1, vv.w, acc1[4 * c + 3]);
        }
    }
    {
        float inv = 1.0f / l0;
        float* cb = ctx + ((size_t)t0 * BB + b) * 72 + hh * 18;
#pragma unroll
        for (int d = 0; d < 18; ++d) cb[d] = acc0[d] * inv;
    }
    if (two) {
        float inv = 1.0f / l1;
        float* cb = ctx + ((size_t)t1 * BB + b) * 72 + hh * 18;
#pragma unroll
        for (int d = 0; d < 18; ++d) cb[d] = acc1[d] * inv;
    }
}

// ---------------------------------------------------------------- h = LN(h + ctx@Wout.T+b) ; MFMA split-bf16
// Wave = 16 rows. 5 N-tiles of 16 (cols >=72 clamped, never stored).
// LN per row via __shfl_xor over the 16-lane quad group.
__global__ __launch_bounds__(256, 1) void k_outln(const float* __restrict__ ctx,
                                                  const unsigned short* __restrict__ Ohi,
                                                  const unsigned short* __restrict__ Olo,
                                                  const float* __restrict__ bias,
                                                  const float* __restrict__ g,
                                                  const float* __restrict__ beta,
                                                  float* __restrict__ h) {
    int tid = threadIdx.x;
    int w = tid >> 6;
    int lane = tid & 63;
    int n16 = lane & 15;
    int quad = lane >> 4;
    int m0 = blockIdx.x * 64 + w * 16;
    int r = m0 + n16;
    short8 Ahi[3], Alo[3];
#pragma unroll
    for (int s = 0; s < 3; ++s) {
        int k0 = s * 32 + quad * 8;
        float v[8];
        if (k0 < 72) {
            const float4* ap = (const float4*)(ctx + (size_t)r * 72 + k0);
            float4 v0 = ap[0], v1 = ap[1];
            v[0] = v0.x; v[1] = v0.y; v[2] = v0.z; v[3] = v0.w;
            v[4] = v1.x; v[5] = v1.y; v[6] = v1.z; v[7] = v1.w;
        } else {
#pragma unroll
            for (int j = 0; j < 8; ++j) v[j] = 0.f;
        }
        short8 ph, pl;
#pragma unroll
        for (int j = 0; j < 8; ++j) {
            unsigned short hi = f2bf_rn(v[j]);
            ph[j] = (short)hi;
            pl[j] = (short)f2bf_rn(v[j] - bf2f(hi));
        }
        Ahi[s] = ph; Alo[s] = pl;
    }
    f32x4 acc[5];
#pragma unroll
    for (int t = 0; t < 5; ++t) acc[t] = (f32x4){0.f, 0.f, 0.f, 0.f};
#pragma unroll
    for (int t = 0; t < 5; ++t) {
        int o = t * 16 + n16;
        int oc = (o > 71) ? 71 : o;
        const short8* bh = (const short8*)(Ohi + (size_t)oc * 96);
        const short8* bl = (const short8*)(Olo + (size_t)oc * 96);
        f32x4 a = acc[t];
#pragma unroll
        for (int s = 0; s < 3; ++s) {
            short8 Bh = bh[s * 4 + quad];
            short8 Bl = bl[s * 4 + quad];
            a = __builtin_amdgcn_mfma_f32_16x16x32_bf16(Ahi[s], Bh, a, 0, 0, 0);
            a = __builtin_amdgcn_mfma_f32_16x16x32_bf16(Ahi[s], Bl, a, 0, 0, 0);
            a = __builtin_amdgcn_mfma_f32_16x16x32_bf16(Alo[s], Bh, a, 0, 0, 0);
        }
        acc[t] = a;
    }
    float vals[5][4];
#pragma unroll
    for (int t = 0; t < 5; ++t) {
        int o = t * 16 + n16;
        bool valid = (o < 72);
        float bb = valid ? bias[o] : 0.f;
#pragma unroll
        for (int reg = 0; reg < 4; ++reg) {
            int row = m0 + quad * 4 + reg;
            float hv = valid ? h[(size_t)row * 72 + o] : 0.f;
            vals[t][reg] = acc[t][reg] + bb + hv;
        }
    }
#pragma unroll
    for (int reg = 0; reg < 4; ++reg) {
        float s = 0.f, q = 0.f;
#pragma unroll
        for (int t = 0; t < 5; ++t) {
            int o = t * 16 + n16;
            if (o < 72) { s += vals[t][reg]; q = fmaf(vals[t][reg], vals[t][reg], q); }
        }
#pragma unroll
        for (int m = 1; m < 16; m <<= 1) { s += __shfl_xor(s, m); q += __shfl_xor(q, m); }
        float mu = s / 72.0f;
        float var = fmaxf(q / 72.0f - mu * mu, 0.0f);
        float rstd = 1.0f / sqrtf(var + 1e-5f);
        int row = m0 + quad * 4 + reg;
#pragma unroll
        for (int t = 0; t < 5; ++t) {
            int o = t * 16 + n16;
            if (o < 72)
                h[(size_t)row * 72 + o] = (vals[t][reg] - mu) * rstd * g[o] + beta[o];
        }
    }
}

// ---------------------------------------------------------------- h = LN(h + relu(h@ff1.T)@ff2.T+b) ; MFMA split-bf16
// Stage 1: hid[16rows x 128] per wave (LDS, wave-private -> no barrier).
// Stage 2: 5 N-tiles x 4 k-steps. LN epilogue via quad shuffles.
__global__ __launch_bounds__(256, 1) void k_ffln(const unsigned short* __restrict__ F1hi,
                                                 const unsigned short* __restrict__ F1lo,
                                                 const float* __restrict__ b1,
                                                 const unsigned short* __restrict__ F2hi,
                                                 const unsigned short* __restrict__ F2lo,
                                                 const float* __restrict__ b2,
                                                 const float* __restrict__ g,
                                                 const float* __restrict__ beta,
                                                 float* __restrict__ h) {
    __shared__ float hid[64][129];
    int tid = threadIdx.x;
    int w = tid >> 6;
    int lane = tid & 63;
    int n16 = lane & 15;
    int quad = lane >> 4;
    int m0 = blockIdx.x * 64 + w * 16;
    int r = m0 + n16;
    // ---- A frags from h (K=72 pad 96)
    short8 Ahi[3], Alo[3];
#pragma unroll
    for (int s = 0; s < 3; ++s) {
        int k0 = s * 32 + quad * 8;
        float v[8];
        if (k0 < 72) {
            const float4* ap = (const float4*)(h + (size_t)r * 72 + k0);
            float4 v0 = ap[0], v1 = ap[1];
            v[0] = v0.x; v[1] = v0.y; v[2] = v0.z; v[3] = v0.w;
            v[4] = v1.x; v[5] = v1.y; v[6] = v1.z; v[7] = v1.w;
        } else {
#pragma unroll
            for (int j = 0; j < 8; ++j) v[j] = 0.f;
        }
        short8 ph, pl;
#pragma unroll
        for (int j = 0; j < 8; ++j) {
            unsigned short hi = f2bf_rn(v[j]);
            ph[j] = (short)hi;
            pl[j] = (short)f2bf_rn(v[j] - bf2f(hi));
        }
        Ahi[s] = ph; Alo[s] = pl;
    }
    // ---- stage 1: 8 tiles over 128 hidden units
#pragma unroll
    for (int t = 0; t < 8; ++t) {
        int j = t * 16 + n16;
        const short8* bh = (const short8*)(F1hi + (size_t)j * 96);
        const short8* bl = (const short8*)(F1lo + (size_t)j * 96);
        f32x4 a = (f32x4){0.f, 0.f, 0.f, 0.f};
#pragma unroll
        for (int s = 0; s < 3; ++s) {
            short8 Bh = bh[s * 4 + quad];
            short8 Bl = bl[s * 4 + quad];
            a = __builtin_amdgcn_mfma_f32_16x16x32_bf16(Ahi[s], Bh, a, 0, 0, 0);
            a = __builtin_amdgcn_mfma_f32_16x16x32_bf16(Ahi[s], Bl, a, 0, 0, 0);
            a = __builtin_amdgcn_mfma_f32_16x16x32_bf16(Alo[s], Bh, a, 0, 0, 0);
        }
        float bb = b1[j];
#pragma unroll
        for (int reg = 0; reg < 4; ++reg)
            hid[w * 16 + quad * 4 + reg][j] = fmaxf(a[reg] + bb, 0.f);
    }
    // wave-private rows: in-wave lgkmcnt ordering suffices, no barrier
    // ---- stage 2 A frags from LDS (K=128, 4 k-steps)
    short8 A2hi[4], A2lo[4];
#pragma unroll
    for (int s = 0; s < 4; ++s) {
        const float* hp = &hid[w * 16 + n16][s * 32 + quad * 8];
        short8 ph, pl;
#pragma unroll
        for (int j = 0; j < 8; ++j) {
            float v = hp[j];
            unsigned short hi = f2bf_rn(v);
            ph[j] = (short)hi;
            pl[j] = (short)f2bf_rn(v - bf2f(hi));
        }
        A2hi[s] = ph; A2lo[s] = pl;
    }
    // ---- stage 2: 5 tiles over 72 outputs
    f32x4 acc[5];
#pragma unroll
    for (int t = 0; t < 5; ++t) acc[t] = (f32x4){0.f, 0.f, 0.f, 0.f};
#pragma unroll
    for (int t = 0; t < 5; ++t) {
        int o = t * 16 + n16;
        int oc = (o > 71) ? 71 : o;
        const short8* bh = (const short8*)(F2hi + (size_t)oc * 128);
        const short8* bl = (const short8*)(F2lo + (size_t)oc * 128);
        f32x4 a = acc[t];
#pragma unroll
        for (int s = 0; s < 4; ++s) {
            short8 Bh = bh[s * 4 + quad];
            short8 Bl = bl[s * 4 + quad];
            a = __builtin_amdgcn_mfma_f32_16x16x32_bf16(A2hi[s], Bh, a, 0, 0, 0);
            a = __builtin_amdgcn_mfma_f32_16x16x32_bf16(A2hi[s], Bl, a, 0, 0, 0);
            a = __builtin_amdgcn_mfma_f32_16x16x32_bf16(A2lo[s], Bh, a, 0, 0, 0);
        }
        acc[t] = a;
    }
    // ---- epilogue: bias + residual + LN
    float vals[5][4];
#pragma unroll
    for (int t = 0; t < 5; ++t) {
        int o = t * 16 + n16;
        bool valid = (o < 72);
        float bb = valid ? b2[o] : 0.f;
#pragma unroll
        for (int reg = 0; reg < 4; ++reg) {
            int row = m0 + quad * 4 + reg;
            float hv = valid ? h[(size_t)row * 72 + o] : 0.f;
            vals[t][reg] = acc[t][reg] + bb + hv;
        }
    }
#pragma unroll
    for (int reg = 0; reg < 4; ++reg) {
        float s = 0.f, q = 0.f;
#pragma unroll
        for (int t = 0; t < 5; ++t) {
            int o = t * 16 + n16;
            if (o < 72) { s += vals[t][reg]; q = fmaf(vals[t][reg], vals[t][reg], q); }
        }
#pragma unroll
        for (int m = 1; m < 16; m <<= 1) { s += __shfl_xor(s, m); q += __shfl_xor(q, m); }
        float mu = s / 72.0f;
        float var = fmaxf(q / 72.0f - mu * mu, 0.0f);
        float rstd = 1.0f / sqrtf(var + 1e-5f);
        int row = m0 + quad * 4 + reg;
#pragma unroll
        for (int t = 0; t < 5; ++t) {
            int o = t * 16 + n16;
            if (o < 72)
                h[(size_t)row * 72 + o] = (vals[t][reg] - mu) * rstd * g[o] + beta[o];
        }
    }
}

// ---------------------------------------------------------------- masked mean-pool + static emb + 2-layer MLP
__global__ void k_head(const float* __restrict__ h, const int* __restrict__ lengths,
                       const float* __restrict__ statics, const float* __restrict__ W_emb,
                       const float* __restrict__ b_emb, const float* __restrict__ w1,
                       const float* __restrict__ bb1, const float* __restrict__ w2,
                       const float* __restrict__ bb2, float* __restrict__ out) {
    __shared__ float ps2[4][72];
    __shared__ float feat[108];
    __shared__ float hidm[108];
    __shared__ float st[9];
    int b = blockIdx.x, tid = threadIdx.x;
    int w = tid >> 6, lane = tid & 63;
    int len = lengths[b];
    if (tid < 9) st[tid] = statics[b * 9 + tid];
    for (int idx = tid; idx < 288; idx += 256) ((float*)ps2)[idx] = 0.f;
    __syncthreads();
#pragma unroll
    for (int c0 = 0; c0 < 128; c0 += 64) {
        int col = c0 + lane;
        if (col < 72) {
            float s = 0.f;
            for (int t = w; t < len; t += 4) s += h[((size_t)t * BB + b) * 72 + col];
            ps2[w][col] = s;
        }
    }
    __syncthreads();
    if (tid < 72)
        feat[tid] = (ps2[0][tid] + ps2[1][tid] + ps2[2][tid] + ps2[3][tid]) / ((float)len + 1.0f);
    if (tid >= 128 && tid < 164) {
        int o = tid - 128;
        float a = b_emb[o];
#pragma unroll
        for (int i = 0; i < 9; ++i) a = fmaf(st[i], W_emb[o * 9 + i], a);
        feat[72 + o] = a;
    }
    __syncthreads();
    if (tid < 108) {
        float a = bb1[tid];
        for (int i = 0; i < 108; ++i) a = fmaf(feat[i], w1[tid * 108 + i], a);
        hidm[tid] = fmaxf(a, 0.f);
    }
    __syncthreads();
    if (tid < 2) {
        float a = bb2[tid];
        for (int i = 0; i < 108; ++i) a = fmaf(hidm[i], w2[tid * 108 + i], a);
        out[b * 2 + tid] = a;
    }
}

// ---------------------------------------------------------------- final distance reduce
__global__ void k_dist(const float* __restrict__ rowsum, float* __restrict__ out) {
    __shared__ float red[256];
    int tid = threadIdx.x;
    red[tid] = rowsum[tid];
    __syncthreads();
    for (int s = 128; s > 0; s >>= 1) { if (tid < s) red[tid] += red[tid + s]; __syncthreads(); }
    if (tid == 0) out[2 * BB] = red[0] / 65536.0f;
}

extern "C" void kernel_launch(void* const* d_in, const int* in_sizes, int n_in,
                              void* d_out, int out_size, void* d_ws, size_t ws_size,
                              hipStream_t stream) {
    const float* src     = (const float*)d_in[0];
    const float* statics = (const float*)d_in[1];
    const float* times   = (const float*)d_in[2];
    const int*   lengths = (const int*)d_in[3];
    const float* W_enc = (const float*)d_in[4];  const float* b_enc = (const float*)d_in[5];
    const float* W_emb = (const float*)d_in[6];  const float* b_emb = (const float*)d_in[7];
    const float* Wq = (const float*)d_in[8];     const float* bq = (const float*)d_in[9];
    const float* Wk = (const float*)d_in[10];    const float* bk = (const float*)d_in[11];
    const float* Wv = (const float*)d_in[12];    const float* bv = (const float*)d_in[13];
    const float* Wskip = (const float*)d_in[14]; const float* bskip = (const float*)d_in[15];
    const float* enc_in_w = (const float*)d_in[16];  const float* enc_in_b = (const float*)d_in[17];
    const float* enc_out_w = (const float*)d_in[18]; const float* enc_out_b = (const float*)d_in[19];
    const float* ff1_w = (const float*)d_in[20]; const float* ff1_b = (const float*)d_in[21];
    const float* ff2_w = (const float*)d_in[22]; const float* ff2_b = (const float*)d_in[23];
    const float* ln1_g = (const float*)d_in[24]; const float* ln1_b = (const float*)d_in[25];
    const float* ln2_g = (const float*)d_in[26]; const float* ln2_b = (const float*)d_in[27];
    const float* w1 = (const float*)d_in[28];    const float* bb1 = (const float*)d_in[29];
    const float* w2 = (const float*)d_in[30];    const float* bb2 = (const float*)d_in[31];
    float* out = (float*)d_out;

    float* p = (float*)d_ws;
    float* x    = p; p += (size_t)ROWS * 36;
    float* h    = p; p += (size_t)ROWS * 72;
    float* qkv  = p; p += (size_t)ROWS * 216;
    float* ctx  = p; p += (size_t)ROWS * 72;
    float* qg   = p; p += (size_t)36 * BB * 36;
    float* kg   = p; p += (size_t)36 * BB * 36;
    float* vg   = p; p += (size_t)36 * BB * 36;
    float* Abuf = p; p += (size_t)BB * 1296;
    float* sqv  = p; p += BB;
    float* rsum = p; p += BB;
    float* ts   = p; p += 32;
    unsigned short* Whi  = (unsigned short*)p; p += (2 * 216 * 96) / 2;
    unsigned short* Wlo  = (unsigned short*)p; p += (2 * 216 * 96) / 2;
    unsigned short* F1hi = (unsigned short*)p; p += (2 * 128 * 96) / 2;
    unsigned short* F1lo = (unsigned short*)p; p += (2 * 128 * 96) / 2;
    unsigned short* F2hi = (unsigned short*)p; p += (2 * 72 * 128) / 2;
    unsigned short* F2lo = (unsigned short*)p; p += (2 * 72 * 128) / 2;
    unsigned short* Ohi  = (unsigned short*)p; p += (2 * 72 * 96) / 2;
    unsigned short* Olo  = (unsigned short*)p; p += (2 * 72 * 96) / 2;

    k_prep<<<162, 256, 0, stream>>>(enc_in_w, ff1_w, ff2_w, enc_out_w,
                                    Whi, Wlo, F1hi, F1lo, F2hi, F2lo, Ohi, Olo, ts);
    k_enc1<<<dim3(TT, 4), 256, 0, stream>>>(src, W_enc, b_enc, x);
    k_enc2<<<dim3(TT, 4), 256, 0, stream>>>(x, Wskip, bskip, h);
    k_pe<<<(ROWS * 36) / 256, 256, 0, stream>>>(times, ts, h);
    k_graph_qkv<<<dim3(36, 12), 256, 0, stream>>>(x, Wq, bq, Wk, bk, Wv, bv, qg, kg, vg);
    k_graph_attn<<<BB, 128, 0, stream>>>(qg, kg, vg, h, Abuf, sqv);
    k_gram<<<BB, 256, 0, stream>>>(Abuf, sqv, rsum);
    for (int l = 0; l < 2; ++l) {
        k_qkv<<<ROWS / 64, 256, 0, stream>>>(h, Whi + (size_t)l * 216 * 96,
                                             Wlo + (size_t)l * 216 * 96,
                                             enc_in_b + l * 216, qkv);
        k_attn<<<BB * 4, 128, 0, stream>>>(qkv, lengths, ctx);
        k_outln<<<ROWS / 64, 256, 0, stream>>>(ctx, Ohi + (size_t)l * 72 * 96,
                                               Olo + (size_t)l * 72 * 96, enc_out_b + l * 72,
                                               ln1_g + l * 72, ln1_b + l * 72, h);
        k_ffln<<<ROWS / 64, 256, 0, stream>>>(F1hi + (size_t)l * 128 * 96,
                                              F1lo + (size_t)l * 128 * 96, ff1_b + l * 128,
                                              F2hi + (size_t)l * 72 * 128,
                                              F2lo + (size_t)l * 72 * 128, ff2_b + l * 72,
                                              ln2_g + l * 72, ln2_b + l * 72, h);
    }
    k_head<<<BB, 256, 0, stream>>>(h, lengths, statics, W_emb, b_emb, w1, bb1, w2, bb2, out);
    k_dist<<<1, 256, 0, stream>>>(rsum, out);
}